// Round 12
// baseline (394.750 us; speedup 1.0000x reference)
//
#include <hip/hip_runtime.h>
#include <hip/hip_bf16.h>
#include <math.h>

#define N0 4096
#define NM1 8192

// workspace float offsets
#define OFF_XL1 0
#define OFF_XL2 65536
#define OFF_UL1 131072
#define OFF_UL2 196608
#define OFF_INV 262144       // 4096
#define OFF_PB  266240       // 4*65536
#define OFF_PX  528384       // 8*65536
#define OFF_PU  1052672      // 8*65536
#define OFF_PRS 1576960      // 8*4096
#define OFF_BAR 1609728      // int region from here
#define REL_OFF 6240         // 6 barriers * 65 counter-slots * 16 ints
#define BAR_INTS 6256

// ---------------------------------------------------------------------------
// two-level grid barrier, variable grid: G/32 groups (<=64) -> root -> release.
// G is ALWAYS sized to measured occupancy (see kernel_launch), so all blocks
// are co-resident by construction -> no deadlock. Protocol bit-identical-
// validated in R3/R4/R6.
// ---------------------------------------------------------------------------
__device__ __forceinline__ void grid_barrier(int* bar, int bi, int ngroups) {
  __syncthreads();
  if (threadIdx.x == 0) {
    const int gid = blockIdx.x >> 5;           // 0..ngroups-1
    int* grp  = bar + (bi * 65 + gid) * 16;
    int* root = bar + (bi * 65 + 64) * 16;
    int* rel  = bar + REL_OFF;
    if (__hip_atomic_fetch_add(grp, 1, __ATOMIC_ACQ_REL, __HIP_MEMORY_SCOPE_AGENT) == 31) {
      if (__hip_atomic_fetch_add(root, 1, __ATOMIC_ACQ_REL, __HIP_MEMORY_SCOPE_AGENT) == ngroups - 1) {
        __hip_atomic_store(rel, bi + 1, __ATOMIC_RELEASE, __HIP_MEMORY_SCOPE_AGENT);
      }
    }
    while (__hip_atomic_load(rel, __ATOMIC_ACQUIRE, __HIP_MEMORY_SCOPE_AGENT) < bi + 1) {
      __builtin_amdgcn_s_sleep(2);
    }
  }
  __syncthreads();
}

// butterfly reduce-scatter: 2*NV values -> NV, exchanging with lane^d.
template<int NV>
__device__ __forceinline__ void red_scatter(float* v, const int d, const int lane) {
  const bool up = (lane & d) != 0;
  #pragma unroll
  for (int i = 0; i < NV; ++i) {
    float send = up ? v[i] : v[i + NV];
    float recv = __shfl_xor(send, d);
    float keep = up ? v[i + NV] : v[i];
    v[i] = keep + recv;
  }
}

// ---------------------------------------------------------------------------
// b1 tile (R10 body verbatim): pB[s] = B1 @ x1.  tile bid: s=bid&3, rg=bid>>2.
// ---------------------------------------------------------------------------
__device__ __forceinline__ void b1_phase(const float* __restrict__ A,
                                         const float* __restrict__ X,
                                         float* __restrict__ pP,
                                         float4* Bs, int bid) {
  const int tid  = threadIdx.x;
  const int wv   = tid >> 6;
  const int lane = tid & 63;
  const int q    = lane >> 5;
  const int ml   = lane & 31;
  const int s    = bid & 3;
  const int rg   = bid >> 2;              // 0..511
  const int row0 = rg * 8 + wv * 2;
  const int mb   = s * 2048;

  const float* A0 = A + (size_t)row0 * NM1 + mb + ml * 4;
  const float* A1 = A0 + NM1;
  const int j0 = q * 2;
  const int jj = tid & 3;
  const int mt = tid >> 2;                // 0..63

  float acc[16];
  #pragma unroll
  for (int i = 0; i < 16; ++i) acc[i] = 0.0f;

  #pragma unroll 1
  for (int ch = 0; ch < 8; ++ch) {        // 256-row chunks
    __syncthreads();
    #pragma unroll
    for (int k = 0; k < 4; ++k) {
      const int m = mt + 64 * k;
      Bs[(m * 4 + jj) ^ ((m >> 2) & 7)] =
          *(const float4*)(X + (size_t)(mb + ch * 256 + m) * 16 + jj * 4);
    }
    __syncthreads();
    #pragma unroll
    for (int il = 0; il < 2; ++il) {
      const int it = ch * 2 + il;
      const float4 a0 = *(const float4*)(A0 + it * 128);
      const float4 a1 = *(const float4*)(A1 + it * 128);
      #pragma unroll
      for (int v = 0; v < 4; ++v) {
        const int mm = il * 128 + ml * 4 + v;     // local row in chunk
        const int h = (mm >> 2) & 7;
        const float4 b0  = Bs[(mm * 4 + j0) ^ h];
        const float4 b1v = Bs[(mm * 4 + j0 + 1) ^ h];
        const float av0 = (&a0.x)[v];
        const float av1 = (&a1.x)[v];
        acc[0]  += av0 * b0.x;   acc[1]  += av0 * b0.y;
        acc[2]  += av0 * b0.z;   acc[3]  += av0 * b0.w;
        acc[4]  += av0 * b1v.x;  acc[5]  += av0 * b1v.y;
        acc[6]  += av0 * b1v.z;  acc[7]  += av0 * b1v.w;
        acc[8]  += av1 * b0.x;   acc[9]  += av1 * b0.y;
        acc[10] += av1 * b0.z;   acc[11] += av1 * b0.w;
        acc[12] += av1 * b1v.x;  acc[13] += av1 * b1v.y;
        acc[14] += av1 * b1v.z;  acc[15] += av1 * b1v.w;
      }
    }
  }

  red_scatter<8>(acc, 1, lane);
  red_scatter<4>(acc, 2, lane);
  red_scatter<2>(acc, 4, lane);
  red_scatter<1>(acc, 8, lane);
  const float tot = acc[0] + __shfl_xor(acc[0], 16);

  if (ml < 16) {
    const int r = ml & 1;
    const int c = 4 * ((ml >> 1) & 1) + 2 * ((ml >> 2) & 1) + ((ml >> 3) & 1);
    pP[(size_t)(s * 65536) + (row0 + r) * 16 + q * 8 + c] = tot;
  }
}

// ---------------------------------------------------------------------------
// cheb tile (R10 body verbatim + R4 SUMU staging). tile bid: s=bid&7, rg=bid>>3.
// ---------------------------------------------------------------------------
template<bool RS, bool SUMU>
__device__ __forceinline__ void cheb_phase(const float* __restrict__ A,
                                           const float* __restrict__ cx,
                                           const float* __restrict__ cu,
                                           float* __restrict__ pX,
                                           float* __restrict__ pU,
                                           float* __restrict__ pRS,
                                           float4* Bs, int bid) {
  const int tid  = threadIdx.x;
  const int wv   = tid >> 6;
  const int lane = tid & 63;
  const int q    = lane >> 3;
  const int ml   = lane & 7;
  const int s    = bid & 7;
  const int rg   = bid >> 3;              // 0..255
  const int row0 = rg * 16 + wv * 4;
  const int mb   = s * 512;

  const float* Ab = A + (size_t)row0 * N0 + mb + ml * 4;
  const int jj = tid & 7;
  const int mt = tid >> 3;                // 0..31
  const float* sbase = (jj < 4) ? cx : cu;
  const int joff = (jj & 3) * 4;

  float acc[16];
  #pragma unroll
  for (int i = 0; i < 16; ++i) acc[i] = 0.0f;
  float rs[4] = {0.0f, 0.0f, 0.0f, 0.0f};

  #pragma unroll 1
  for (int ch = 0; ch < 4; ++ch) {        // 128-row chunks
    __syncthreads();
    #pragma unroll
    for (int k = 0; k < 4; ++k) {
      const int m = mt + 32 * k;
      float4 val;
      if constexpr (SUMU) {
        if (jj >= 4) {
          const float* pb = cu + (size_t)(mb + ch * 128 + m) * 16 + joff;
          const float4 t0 = *(const float4*)(pb);
          const float4 t1 = *(const float4*)(pb + 65536);
          const float4 t2 = *(const float4*)(pb + 131072);
          const float4 t3 = *(const float4*)(pb + 196608);
          val = make_float4(t0.x + t1.x + t2.x + t3.x,
                            t0.y + t1.y + t2.y + t3.y,
                            t0.z + t1.z + t2.z + t3.z,
                            t0.w + t1.w + t2.w + t3.w);
        } else {
          val = *(const float4*)(cx + (size_t)(mb + ch * 128 + m) * 16 + joff);
        }
      } else {
        val = *(const float4*)(sbase + (size_t)(mb + ch * 128 + m) * 16 + joff);
      }
      Bs[(m * 8 + jj) ^ ((m >> 2) & 7)] = val;
    }
    __syncthreads();
    #pragma unroll
    for (int il = 0; il < 4; ++il) {
      const int it = ch * 4 + il;
      float4 b[4];
      #pragma unroll
      for (int v = 0; v < 4; ++v) {
        const int mm = il * 32 + ml * 4 + v;      // local row in chunk
        b[v] = Bs[(mm * 8 + q) ^ ((mm >> 2) & 7)];
      }
      #pragma unroll
      for (int r = 0; r < 4; ++r) {
        const float4 a = *(const float4*)(Ab + (size_t)r * N0 + it * 32);
        #pragma unroll
        for (int v = 0; v < 4; ++v) {
          const float av = (&a.x)[v];
          acc[r*4+0] += av * b[v].x;  acc[r*4+1] += av * b[v].y;
          acc[r*4+2] += av * b[v].z;  acc[r*4+3] += av * b[v].w;
          if constexpr (RS) rs[r] += av;
        }
      }
    }
  }

  red_scatter<8>(acc, 1, lane);
  red_scatter<4>(acc, 2, lane);
  red_scatter<2>(acc, 4, lane);
  const int r   = 2 * (ml & 1) + ((ml >> 1) & 1);
  const int ch2 = (ml >> 2) & 1;
  float* base = (q >> 2) ? pU : pX;
  *(float2*)(base + (size_t)(s * 65536) + (row0 + r) * 16 + (q & 3) * 4 + ch2 * 2) =
      make_float2(acc[0], acc[1]);

  if constexpr (RS) {
    red_scatter<2>(rs, 1, lane);
    red_scatter<1>(rs, 2, lane);
    const float rsum = rs[0] + __shfl_xor(rs[0], 4);
    if (q == 0 && ml < 4) {
      const int rr = 2 * (ml & 1) + ((ml >> 1) & 1);
      pRS[s * N0 + row0 + rr] = rsum;
    }
  }
}

// ---------------------------------------------------------------------------
// norm (blocks 0..255): sum 8 partials, aggr_norm. FIRST computes inv.
// ---------------------------------------------------------------------------
template<bool FIRST>
__device__ __forceinline__ void norm_phase(const float* __restrict__ pX,
                                           const float* __restrict__ pU,
                                           const float* __restrict__ pRS,
                                           float* __restrict__ inv,
                                           float* __restrict__ ox,
                                           float* __restrict__ ou) {
  const int idx = blockIdx.x * 256 + threadIdx.x;   // < 65536
  const int row = idx >> 4;
  float iv;
  if constexpr (FIRST) {
    float rsv = 0.0f;
    #pragma unroll
    for (int s2 = 0; s2 < 8; ++s2) rsv += pRS[s2 * N0 + row];
    iv = 1.0f / rsv;
    if (!isfinite(iv)) iv = 0.0f;
    if ((idx & 15) == 0) inv[row] = iv;
  } else {
    iv = inv[row];
  }
  float xv = 0.0f, uv = 0.0f;
  #pragma unroll
  for (int s2 = 0; s2 < 8; ++s2) { xv += pX[s2*65536 + idx]; uv += pU[s2*65536 + idx]; }
  xv *= iv; uv *= iv;
  ox[idx] = isfinite(xv) ? xv : 0.0f;
  ou[idx] = isfinite(uv) ? uv : 0.0f;
}

// ---------------------------------------------------------------------------
// einsum (blocks 0..255): k=3,7 norm-fused from pX/pU; k=4 summed from pB.
// ---------------------------------------------------------------------------
__device__ __forceinline__ void einsum_phase(const float* __restrict__ x0,
                                             const float* __restrict__ xl1,
                                             const float* __restrict__ xl2,
                                             const float* __restrict__ pB,
                                             const float* __restrict__ ul1,
                                             const float* __restrict__ ul2,
                                             const float* __restrict__ pX,
                                             const float* __restrict__ pU,
                                             const float* __restrict__ inv,
                                             const float* __restrict__ W,
                                             float* __restrict__ y,
                                             float* smem) {
  float* Wl = smem;              // 2048 floats
  float* xs = smem + 2048;       // 2048 floats: [r][k][i]
  const int t = threadIdx.x;
  const int row0 = blockIdx.x * 16;
  #pragma unroll
  for (int k = 0; k < 8; ++k) Wl[t + 256 * k] = W[t + 256 * k];
  const int r = t >> 4;
  const int i = t & 15;
  const int g = (row0 + r) * 16 + i;
  const float iv = inv[row0 + r];
  float x3 = 0.0f, u3 = 0.0f;
  #pragma unroll
  for (int s2 = 0; s2 < 8; ++s2) { x3 += pX[s2*65536 + g]; u3 += pU[s2*65536 + g]; }
  x3 *= iv; u3 *= iv;
  if (!isfinite(x3)) x3 = 0.0f;
  if (!isfinite(u3)) u3 = 0.0f;
  const float uval = pB[g] + pB[65536 + g] + pB[131072 + g] + pB[196608 + g];
  xs[r*128 + 0*16 + i] = x0[g];
  xs[r*128 + 1*16 + i] = xl1[g];
  xs[r*128 + 2*16 + i] = xl2[g];
  xs[r*128 + 3*16 + i] = x3;
  xs[r*128 + 4*16 + i] = uval;
  xs[r*128 + 5*16 + i] = ul1[g];
  xs[r*128 + 6*16 + i] = ul2[g];
  xs[r*128 + 7*16 + i] = u3;
  __syncthreads();
  const int o = t & 15;
  float a = 0.0f;
  #pragma unroll
  for (int ii = 0; ii < 16; ++ii) {
    #pragma unroll
    for (int k = 0; k < 8; ++k)
      a += xs[r*128 + k*16 + ii] * Wl[(ii*16 + o)*8 + k];
  }
  y[(row0 + r) * 16 + o] = a;
}

__global__ void init_bar_kernel(int* bar) {
  for (int i = threadIdx.x; i < BAR_INTS; i += 256) bar[i] = 0;
}

// ---------------------------------------------------------------------------
// Persistent mega: grid G sized by the HOST to the measured occupancy of THIS
// kernel (no launch_bounds min-waves clamp -> no spill; grid <= resident
// capacity -> no deadlock). Tile loops stride gridDim.x; per-tile math is
// independent of G -> bit-identical output for any G.
// ---------------------------------------------------------------------------
__global__ __launch_bounds__(256)
void mega_kernel(const float* __restrict__ x0, const float* __restrict__ x1,
                 const float* __restrict__ L0, const float* __restrict__ B1,
                 const float* __restrict__ W0, float* __restrict__ ws,
                 int* __restrict__ bar, float* __restrict__ y) {
  __shared__ float4 Bs[1024];    // 16 KiB, reused by all phases
  float* xl1 = ws + OFF_XL1;
  float* xl2 = ws + OFF_XL2;
  float* ul1 = ws + OFF_UL1;
  float* ul2 = ws + OFF_UL2;
  float* inv = ws + OFF_INV;
  float* pB  = ws + OFF_PB;
  float* pX  = ws + OFF_PX;
  float* pU  = ws + OFF_PU;
  float* pRS = ws + OFF_PRS;
  const int G = gridDim.x;
  const int ngroups = G >> 5;    // G is a multiple of 256

  // P0: b1 partials
  #pragma unroll 1
  for (int t = blockIdx.x; t < 2048; t += G) b1_phase(B1, x1, pB, Bs, t);
  grid_barrier(bar, 0, ngroups);

  // P1: cheb step 1 (stages u from pB, computes rowsum)
  #pragma unroll 1
  for (int t = blockIdx.x; t < 2048; t += G)
    cheb_phase<true, true>(L0, x0, pB, pX, pU, pRS, Bs, t);
  grid_barrier(bar, 1, ngroups);

  // P2: inv + normalize -> xl1, ul1
  if (blockIdx.x < 256) norm_phase<true>(pX, pU, pRS, inv, xl1, ul1);
  grid_barrier(bar, 2, ngroups);

  // P3: cheb step 2
  #pragma unroll 1
  for (int t = blockIdx.x; t < 2048; t += G)
    cheb_phase<false, false>(L0, xl1, ul1, pX, pU, pRS, Bs, t);
  grid_barrier(bar, 3, ngroups);

  // P4: normalize -> xl2, ul2
  if (blockIdx.x < 256) norm_phase<false>(pX, pU, pRS, inv, xl2, ul2);
  grid_barrier(bar, 4, ngroups);

  // P5: cheb step 3
  #pragma unroll 1
  for (int t = blockIdx.x; t < 2048; t += G)
    cheb_phase<false, false>(L0, xl2, ul2, pX, pU, pRS, Bs, t);
  grid_barrier(bar, 5, ngroups);

  // P6: einsum with step-3 norm fused, u from pB
  if (blockIdx.x < 256)
    einsum_phase(x0, xl1, xl2, pB, ul1, ul2, pX, pU, inv, W0, y, (float*)Bs);
}

// ---------------------------------------------------------------------------
extern "C" void kernel_launch(void* const* d_in, const int* in_sizes, int n_in,
                              void* d_out, int out_size, void* d_ws, size_t ws_size,
                              hipStream_t stream) {
  (void)in_sizes; (void)n_in; (void)out_size; (void)ws_size;
  const float* x0 = (const float*)d_in[0];
  const float* x1 = (const float*)d_in[1];
  const float* L0 = (const float*)d_in[3];
  const float* B1 = (const float*)d_in[8];
  const float* W0 = (const float*)d_in[10];

  float* ws = (float*)d_ws;
  int* bar = (int*)(ws + OFF_BAR);

  // Size the persistent grid to the occupancy the compiler ACTUALLY produced.
  // Host-side query: graph-capture-safe, deterministic.
  int occ = 0;
  hipOccupancyMaxActiveBlocksPerMultiprocessor(&occ, mega_kernel, 256, 0);
  if (occ < 1) occ = 1;
  if (occ > 8) occ = 8;
  int G = occ * 256;
  if (G > 2048) G = 2048;

  init_bar_kernel<<<1, 256, 0, stream>>>(bar);
  mega_kernel<<<G, 256, 0, stream>>>(x0, x1, L0, B1, W0, ws, bar, (float*)d_out);
}

// Round 13
// 142.009 us; speedup vs baseline: 2.7797x; 2.7797x over previous
//
#include <hip/hip_runtime.h>
#include <hip/hip_bf16.h>
#include <math.h>

#define N0 4096
#define NM1 8192

// workspace float offsets
#define OFF_U   0            // 65536
#define OFF_XL1 65536
#define OFF_XL2 131072
#define OFF_UL1 196608
#define OFF_UL2 262144
#define OFF_INV 327680       // 4096
#define OFF_PB  331776       // 4*65536
#define OFF_PX  593920       // 8*65536
#define OFF_PU  1118208      // 8*65536
#define OFF_PRS 1642496      // 8*4096

// butterfly reduce-scatter: 2*NV values -> NV, exchanging with lane^d.
template<int NV>
__device__ __forceinline__ void red_scatter(float* v, const int d, const int lane) {
  const bool up = (lane & d) != 0;
  #pragma unroll
  for (int i = 0; i < NV; ++i) {
    float send = up ? v[i] : v[i + NV];
    float recv = __shfl_xor(send, d);
    float keep = up ? v[i + NV] : v[i];
    v[i] = keep + recv;
  }
}

// ---------------------------------------------------------------------------
// Rowsums of L0, all 8 m-splits: pRS[s][row] = sum over the split's m-chain.
// Chain (it 0..15, v 0..3 at m = s*512+it*32+ml*4+v) and butterfly tree
// (d=1,2,4 over 8 ml-slices) reproduce cheb1's old rowsum EXACTLY
// (shfl-xor allreduce in d order == red_scatter chain; IEEE add commutes).
// Fully coalesced (lane=r*8+ml -> 1KB/instr). Also pre-warms L3 with L0.
// grid 512 = 128 rgrp x 4 sg; block 256 (4 waves x 8 rows).
// ---------------------------------------------------------------------------
__global__ __launch_bounds__(256)
void rowsum_kernel(const float* __restrict__ A,   // [4096][4096]
                   float* __restrict__ pRS)       // [8][4096]
{
  const int tid  = threadIdx.x;
  const int wv   = tid >> 6;
  const int lane = tid & 63;
  const int r    = lane >> 3;
  const int ml   = lane & 7;
  const int rgrp = blockIdx.x >> 2;
  const int sg   = blockIdx.x & 3;
  const int row  = rgrp * 32 + wv * 8 + r;

  #pragma unroll 1
  for (int si = 0; si < 2; ++si) {
    const int s = sg * 2 + si;
    const float* base = A + (size_t)row * N0 + s * 512 + ml * 4;
    float rs = 0.0f;
    #pragma unroll
    for (int it = 0; it < 16; ++it) {
      const float4 a = *(const float4*)(base + it * 32);
      rs += a.x; rs += a.y; rs += a.z; rs += a.w;
    }
    rs += __shfl_xor(rs, 1);
    rs += __shfl_xor(rs, 2);
    rs += __shfl_xor(rs, 4);
    if (ml == 0) pRS[s * N0 + row] = rs;
  }
}

// ---------------------------------------------------------------------------
// pB[s] = B1[rows, m-range(s)] @ x1 (R10 verbatim). LDS-staged X, 16 KiB.
// grid 2048 = 512 rg x 4 s; 4 waves x 2 rows/wave. Bit-identical chain.
// ---------------------------------------------------------------------------
__global__ __launch_bounds__(256)
void b1_kernel(const float* __restrict__ A,    // [4096][8192]
               const float* __restrict__ X,    // [8192][16]
               float* __restrict__ pP)         // [4][4096][16]
{
  __shared__ float4 Bs[1024];                  // 256 m x 4 col-blocks, 16 KiB
  const int tid  = threadIdx.x;
  const int wv   = tid >> 6;
  const int lane = tid & 63;
  const int q    = lane >> 5;
  const int ml   = lane & 31;
  const int s    = blockIdx.x & 3;
  const int rg   = blockIdx.x >> 2;       // 0..511
  const int row0 = rg * 8 + wv * 2;
  const int mb   = s * 2048;

  const float* A0 = A + (size_t)row0 * NM1 + mb + ml * 4;
  const float* A1 = A0 + NM1;
  const int j0 = q * 2;
  const int jj = tid & 3;
  const int mt = tid >> 2;                // 0..63

  float acc[16];
  #pragma unroll
  for (int i = 0; i < 16; ++i) acc[i] = 0.0f;

  #pragma unroll 1
  for (int ch = 0; ch < 8; ++ch) {        // 256-row chunks
    __syncthreads();
    #pragma unroll
    for (int k = 0; k < 4; ++k) {
      const int m = mt + 64 * k;
      Bs[(m * 4 + jj) ^ ((m >> 2) & 7)] =
          *(const float4*)(X + (size_t)(mb + ch * 256 + m) * 16 + jj * 4);
    }
    __syncthreads();
    #pragma unroll
    for (int il = 0; il < 2; ++il) {
      const int it = ch * 2 + il;
      const float4 a0 = *(const float4*)(A0 + it * 128);
      const float4 a1 = *(const float4*)(A1 + it * 128);
      #pragma unroll
      for (int v = 0; v < 4; ++v) {
        const int mm = il * 128 + ml * 4 + v;     // local row in chunk
        const int h = (mm >> 2) & 7;
        const float4 b0  = Bs[(mm * 4 + j0) ^ h];
        const float4 b1v = Bs[(mm * 4 + j0 + 1) ^ h];
        const float av0 = (&a0.x)[v];
        const float av1 = (&a1.x)[v];
        acc[0]  += av0 * b0.x;   acc[1]  += av0 * b0.y;
        acc[2]  += av0 * b0.z;   acc[3]  += av0 * b0.w;
        acc[4]  += av0 * b1v.x;  acc[5]  += av0 * b1v.y;
        acc[6]  += av0 * b1v.z;  acc[7]  += av0 * b1v.w;
        acc[8]  += av1 * b0.x;   acc[9]  += av1 * b0.y;
        acc[10] += av1 * b0.z;   acc[11] += av1 * b0.w;
        acc[12] += av1 * b1v.x;  acc[13] += av1 * b1v.y;
        acc[14] += av1 * b1v.z;  acc[15] += av1 * b1v.w;
      }
    }
  }

  red_scatter<8>(acc, 1, lane);
  red_scatter<4>(acc, 2, lane);
  red_scatter<2>(acc, 4, lane);
  red_scatter<1>(acc, 8, lane);
  const float tot = acc[0] + __shfl_xor(acc[0], 16);

  if (ml < 16) {
    const int r = ml & 1;
    const int c = 4 * ((ml >> 1) & 1) + 2 * ((ml >> 2) & 1) + ((ml >> 3) & 1);
    pP[(size_t)(s * 65536) + (row0 + r) * 16 + q * 8 + c] = tot;
  }
}

// u = sum of 4 b1 partials (left-assoc, as all prior rounds)
__global__ void finalize_u_kernel(const float* __restrict__ pP,
                                  float* __restrict__ u) {
  const int idx = blockIdx.x * 256 + threadIdx.x;   // < 65536
  u[idx] = pP[idx] + pP[65536 + idx] + pP[131072 + idx] + pP[196608 + idx];
}

// ---------------------------------------------------------------------------
// LEAN cheb (used for all 3 steps): pX/pU[s] = L0 @ {cx, cu}. No rowsum, no
// SUMU -> minimal registers (acc16 + b16 + a4), targeting <=64 VGPR for
// 8 blocks/CU (32 waves/CU). LDS-staged B, 16 KiB. Chains bit-identical to
// rounds 4/7/8/9/10 (m = s*512 + it*32 + ml*4 + v; reduce d=1,2,4).
// grid 2048 = 256 rg x 8 s; 4 waves x 4 rows/wave.
// ---------------------------------------------------------------------------
__global__ __launch_bounds__(256)
void cheb_kernel(const float* __restrict__ A,     // [4096][4096]
                 const float* __restrict__ cx,    // [4096][16]
                 const float* __restrict__ cu,    // [4096][16]
                 float* __restrict__ pX,          // [8][4096][16]
                 float* __restrict__ pU)          // [8][4096][16]
{
  __shared__ float4 Bs[1024];                  // 128 m x 8 col-blocks, 16 KiB
  const int tid  = threadIdx.x;
  const int wv   = tid >> 6;
  const int lane = tid & 63;
  const int q    = lane >> 3;
  const int ml   = lane & 7;
  const int s    = blockIdx.x & 7;
  const int rg   = blockIdx.x >> 3;       // 0..255
  const int row0 = rg * 16 + wv * 4;
  const int mb   = s * 512;

  const float* Ab = A + (size_t)row0 * N0 + mb + ml * 4;
  const int jj = tid & 7;
  const int mt = tid >> 3;                // 0..31
  const float* sbase = (jj < 4) ? cx : cu;
  const int joff = (jj & 3) * 4;

  float acc[16];
  #pragma unroll
  for (int i = 0; i < 16; ++i) acc[i] = 0.0f;

  #pragma unroll 1
  for (int ch = 0; ch < 4; ++ch) {        // 128-row chunks
    __syncthreads();
    #pragma unroll
    for (int k = 0; k < 4; ++k) {
      const int m = mt + 32 * k;
      Bs[(m * 8 + jj) ^ ((m >> 2) & 7)] =
          *(const float4*)(sbase + (size_t)(mb + ch * 128 + m) * 16 + joff);
    }
    __syncthreads();
    #pragma unroll
    for (int il = 0; il < 4; ++il) {
      const int it = ch * 4 + il;
      float4 b[4];
      #pragma unroll
      for (int v = 0; v < 4; ++v) {
        const int mm = il * 32 + ml * 4 + v;      // local row in chunk
        b[v] = Bs[(mm * 8 + q) ^ ((mm >> 2) & 7)];
      }
      #pragma unroll
      for (int r = 0; r < 4; ++r) {
        const float4 a = *(const float4*)(Ab + (size_t)r * N0 + it * 32);
        #pragma unroll
        for (int v = 0; v < 4; ++v) {
          const float av = (&a.x)[v];
          acc[r*4+0] += av * b[v].x;  acc[r*4+1] += av * b[v].y;
          acc[r*4+2] += av * b[v].z;  acc[r*4+3] += av * b[v].w;
        }
      }
    }
  }

  // reduce across 8 m-lanes, d-sequence 1,2,4 (as all prior rounds)
  red_scatter<8>(acc, 1, lane);
  red_scatter<4>(acc, 2, lane);
  red_scatter<2>(acc, 4, lane);
  const int r   = 2 * (ml & 1) + ((ml >> 1) & 1);
  const int ch2 = (ml >> 2) & 1;
  float* base = (q >> 2) ? pU : pX;
  *(float2*)(base + (size_t)(s * 65536) + (row0 + r) * 16 + (q & 3) * 4 + ch2 * 2) =
      make_float2(acc[0], acc[1]);
}

// ---------------------------------------------------------------------------
// norm1: inv = 1/sum8(pRS) (nonfinite->0); normalize step-1 partials.
// ---------------------------------------------------------------------------
__global__ void norm1_kernel(const float* __restrict__ pX,
                             const float* __restrict__ pU,
                             const float* __restrict__ pRS,
                             float* __restrict__ inv,
                             float* __restrict__ ox,
                             float* __restrict__ ou) {
  const int idx = blockIdx.x * 256 + threadIdx.x;   // < 65536
  const int row = idx >> 4;
  float rsv = 0.0f;
  #pragma unroll
  for (int s2 = 0; s2 < 8; ++s2) rsv += pRS[s2 * N0 + row];
  float iv = 1.0f / rsv;
  if (!isfinite(iv)) iv = 0.0f;
  if ((idx & 15) == 0) inv[row] = iv;
  float xv = 0.0f, uv = 0.0f;
  #pragma unroll
  for (int s2 = 0; s2 < 8; ++s2) { xv += pX[s2*65536 + idx]; uv += pU[s2*65536 + idx]; }
  xv *= iv; uv *= iv;
  ox[idx] = isfinite(xv) ? xv : 0.0f;
  ou[idx] = isfinite(uv) ? uv : 0.0f;
}

__global__ void norm23_kernel(const float* __restrict__ pX,
                              const float* __restrict__ pU,
                              const float* __restrict__ inv,
                              float* __restrict__ ox,
                              float* __restrict__ ou) {
  const int idx = blockIdx.x * 256 + threadIdx.x;   // < 65536
  const float iv = inv[idx >> 4];
  float xv = 0.0f, uv = 0.0f;
  #pragma unroll
  for (int s2 = 0; s2 < 8; ++s2) { xv += pX[s2*65536 + idx]; uv += pU[s2*65536 + idx]; }
  xv *= iv; uv *= iv;
  ox[idx] = isfinite(xv) ? xv : 0.0f;
  ou[idx] = isfinite(uv) ? uv : 0.0f;
}

// ---------------------------------------------------------------------------
// y0[n,o] = sum_{i,k} xall[n,i,k]*W[i,o,k]; k: 0=x0, 1..3=xlap, 4=u, 5..7=ulap.
// k=3,7 (step-3 norm) fused from pX/pU partials.
// ---------------------------------------------------------------------------
__global__ void einsum_kernel(const float* __restrict__ x0,
                              const float* __restrict__ xl1,
                              const float* __restrict__ xl2,
                              const float* __restrict__ u,
                              const float* __restrict__ ul1,
                              const float* __restrict__ ul2,
                              const float* __restrict__ pX,
                              const float* __restrict__ pU,
                              const float* __restrict__ inv,
                              const float* __restrict__ W,   // [16][16][8]
                              float* __restrict__ y) {
  __shared__ float Wl[2048];
  __shared__ float xs[16 * 128];                 // [r][k][i]
  const int t = threadIdx.x;
  const int row0 = blockIdx.x * 16;
  #pragma unroll
  for (int k = 0; k < 8; ++k) Wl[t + 256 * k] = W[t + 256 * k];
  const int r = t >> 4;
  const int i = t & 15;
  const int g = (row0 + r) * 16 + i;
  const float iv = inv[row0 + r];
  float x3 = 0.0f, u3 = 0.0f;
  #pragma unroll
  for (int s2 = 0; s2 < 8; ++s2) { x3 += pX[s2*65536 + g]; u3 += pU[s2*65536 + g]; }
  x3 *= iv; u3 *= iv;
  if (!isfinite(x3)) x3 = 0.0f;
  if (!isfinite(u3)) u3 = 0.0f;
  xs[r*128 + 0*16 + i] = x0[g];
  xs[r*128 + 1*16 + i] = xl1[g];
  xs[r*128 + 2*16 + i] = xl2[g];
  xs[r*128 + 3*16 + i] = x3;
  xs[r*128 + 4*16 + i] = u[g];
  xs[r*128 + 5*16 + i] = ul1[g];
  xs[r*128 + 6*16 + i] = ul2[g];
  xs[r*128 + 7*16 + i] = u3;
  __syncthreads();
  const int o = t & 15;
  float a = 0.0f;
  #pragma unroll
  for (int ii = 0; ii < 16; ++ii) {
    #pragma unroll
    for (int k = 0; k < 8; ++k)
      a += xs[r*128 + k*16 + ii] * Wl[(ii*16 + o)*8 + k];
  }
  y[(row0 + r) * 16 + o] = a;
}

// ---------------------------------------------------------------------------
extern "C" void kernel_launch(void* const* d_in, const int* in_sizes, int n_in,
                              void* d_out, int out_size, void* d_ws, size_t ws_size,
                              hipStream_t stream) {
  (void)in_sizes; (void)n_in; (void)out_size; (void)ws_size;
  const float* x0 = (const float*)d_in[0];
  const float* x1 = (const float*)d_in[1];
  const float* L0 = (const float*)d_in[3];
  const float* B1 = (const float*)d_in[8];
  const float* W0 = (const float*)d_in[10];

  float* ws  = (float*)d_ws;
  float* u   = ws + OFF_U;
  float* xl1 = ws + OFF_XL1;
  float* xl2 = ws + OFF_XL2;
  float* ul1 = ws + OFF_UL1;
  float* ul2 = ws + OFF_UL2;
  float* inv = ws + OFF_INV;
  float* pB  = ws + OFF_PB;
  float* pX  = ws + OFF_PX;
  float* pU  = ws + OFF_PU;
  float* pRS = ws + OFF_PRS;

  // rowsums of L0 (also warms L3 with L0 for cheb1)
  rowsum_kernel<<<512, 256, 0, stream>>>(L0, pRS);

  // u = b1 @ x_1
  b1_kernel<<<2048, 256, 0, stream>>>(B1, x1, pB);
  finalize_u_kernel<<<256, 256, 0, stream>>>(pB, u);

  // step 1
  cheb_kernel<<<2048, 256, 0, stream>>>(L0, x0, u, pX, pU);
  norm1_kernel<<<256, 256, 0, stream>>>(pX, pU, pRS, inv, xl1, ul1);
  // step 2
  cheb_kernel<<<2048, 256, 0, stream>>>(L0, xl1, ul1, pX, pU);
  norm23_kernel<<<256, 256, 0, stream>>>(pX, pU, inv, xl2, ul2);
  // step 3 (normalization fused into einsum)
  cheb_kernel<<<2048, 256, 0, stream>>>(L0, xl2, ul2, pX, pU);

  // y_0 = einsum('nik,iok->no', x_0_all, weight_0)
  einsum_kernel<<<256, 256, 0, stream>>>(x0, xl1, xl2, u, ul1, ul2,
                                         pX, pU, inv, W0, (float*)d_out);
}